// Round 9
// baseline (527.011 us; speedup 1.0000x reference)
//
#include <hip/hip_runtime.h>
#include <hip/hip_bf16.h>

#define NNODES 20000
#define NEDGES 320000
#define XW 1005          // x row width: 1 + 1000 + 1 + 3
#define MP 20096         // 157 * 128 row-padded M

typedef __attribute__((ext_vector_type(8))) short short8;
typedef __attribute__((ext_vector_type(4))) float f32x4;
typedef __attribute__((ext_vector_type(4))) unsigned short u16x4;

typedef const __attribute__((address_space(1))) short8* g8cp;

__device__ inline void split1(float v, unsigned short& h, unsigned short& l) {
    unsigned u = __float_as_uint(v);
    h = (unsigned short)(u >> 16);
    float hf = __uint_as_float(u & 0xffff0000u);
    l = (unsigned short)(__float_as_uint(v - hf) >> 16);
}

// ================= fused prep über-kernel =================
#define PB_EDGE  1250
#define PB_IDX   1329
#define PB_A1    21329
#define PB_BT1   21841
#define PB_BT2   21969
#define PB_BT3   21985
#define PB_TAB   23549

__device__ inline void bt_split_body(int g, const float* __restrict__ W, int ldw,
                                     int koff, int K, int Kp, int Ncols,
                                     unsigned short* __restrict__ Bh,
                                     unsigned short* __restrict__ Bl) {
    int kp4 = Kp >> 2;
    if (g >= Ncols * kp4) return;
    int n = g / kp4, c4 = (g % kp4) << 2;
    u16x4 h, l;
#pragma unroll
    for (int i = 0; i < 4; ++i) {
        int k = c4 + i;
        float v = (k < K) ? W[(size_t)(koff + k) * ldw + n] : 0.0f;
        unsigned short hh, ll;
        split1(v, hh, ll);
        h[i] = (short)hh; l[i] = (short)ll;
    }
    *(u16x4*)&Bh[(size_t)n * Kp + c4] = h;
    *(u16x4*)&Bl[(size_t)n * Kp + c4] = l;
}

__global__ __launch_bounds__(256) void prep_kernel(
    const float* __restrict__ x, const int* __restrict__ ei, const float* __restrict__ ea,
    const float* __restrict__ layer_table, const float* __restrict__ rel_table,
    const float* __restrict__ color_table,
    const float* __restrict__ W1, const float* __restrict__ W2, const float* __restrict__ W3,
    float* __restrict__ deg, int* __restrict__ counts, int* __restrict__ idx8,
    unsigned short* __restrict__ A1h, unsigned short* __restrict__ A1l,
    unsigned short* __restrict__ Bt1h, unsigned short* __restrict__ Bt1l,
    unsigned short* __restrict__ Bt2h, unsigned short* __restrict__ Bt2l,
    unsigned short* __restrict__ Bt3h, unsigned short* __restrict__ Bt3l,
    float* __restrict__ T) {
    const int b = blockIdx.x;
    const int t = threadIdx.x;
    if (b < PB_EDGE) {
        int e = b * 256 + t;
        if (e >= NEDGES) return;
        int dst = ei[NEDGES + e];
        atomicAdd(&deg[dst], ea[e]);
        atomicAdd(&counts[dst], 1);
    } else if (b < PB_IDX) {
        int i = (b - PB_EDGE) * 256 + t;
        if (i >= NNODES) return;
        const float* r = x + (size_t)i * XW;
        idx8[i * 8 + 0] = (int)(r[0] - 1.0f);
        idx8[i * 8 + 1] = (int)rintf(fabsf(r[1001]) * 10.0f);
        idx8[i * 8 + 2] = (int)r[1002];
        idx8[i * 8 + 3] = (int)r[1003];
        idx8[i * 8 + 4] = (int)r[1004];
    } else if (b < PB_A1) {
        int row = b - PB_IDX;                  // one block per node
        int c4 = t << 2;
        const float* xp = x + (size_t)row * XW + 1 + c4;
        u16x4 h, l;
#pragma unroll
        for (int i = 0; i < 4; ++i) {
            float v = (c4 + i < 1000) ? xp[i] : 0.0f;
            unsigned short hh, ll;
            split1(v, hh, ll);
            h[i] = (short)hh; l[i] = (short)ll;
        }
        *(u16x4*)&A1h[(size_t)row * 1024 + c4] = h;
        *(u16x4*)&A1l[(size_t)row * 1024 + c4] = l;
    } else if (b < PB_BT1) {
        bt_split_body((b - PB_A1) * 256 + t, W1, 512, 250, 1000, 1024, 512, Bt1h, Bt1l);
    } else if (b < PB_BT2) {
        bt_split_body((b - PB_BT1) * 256 + t, W2, 256, 0, 512, 512, 256, Bt2h, Bt2l);
    } else if (b < PB_BT3) {
        bt_split_body((b - PB_BT2) * 256 + t, W3, 64, 0, 256, 256, 64, Bt3h, Bt3l);
    } else {
        int g = (b - PB_BT3) * 256 + t;
        if (g >= 782 * 512) return;
        int row = g >> 9, col = g & 511;
        float acc = 0.0f;
        if (row < 3) {
            for (int k = 0; k < 250; ++k)
                acc += layer_table[row * 250 + k] * W1[(size_t)k * 512 + col];
        } else if (row < 14) {
            int r = row - 3;
            for (int k = 0; k < 250; ++k)
                acc += rel_table[r * 250 + k] * W1[(size_t)(1250 + k) * 512 + col];
        } else {
            int r = row - 14;
            int j = r >> 8, v = r & 255;
            int base = 1500 + 85 * j;
            for (int k = 0; k < 85; ++k)
                acc += color_table[v * 85 + k] * W1[(size_t)(base + k) * 512 + col];
        }
        T[(size_t)row * 512 + col] = acc;
    }
}

// ================= 3-phase parallel scan (+ dinv folded into phase 1) =================

__global__ __launch_bounds__(1024) void scan_p1_kernel(const int* __restrict__ counts,
                                                       int* __restrict__ bsum,
                                                       const float* __restrict__ deg,
                                                       float* __restrict__ dinv, int n) {
    int b = blockIdx.x;
    if (b < 20) {
        __shared__ int ws[16];
        int t = threadIdx.x, lane = t & 63, wid = t >> 6;
        int i = b * 1024 + t;
        int v = (i < n) ? counts[i] : 0;
#pragma unroll
        for (int d = 32; d; d >>= 1) v += __shfl_down(v, d, 64);
        if (lane == 0) ws[wid] = v;
        __syncthreads();
        if (wid == 0) {
            int s = (lane < 16) ? ws[lane] : 0;
#pragma unroll
            for (int d = 8; d; d >>= 1) s += __shfl_down(s, d, 64);
            if (lane == 0) bsum[b] = s;
        }
    } else {
        int i = (b - 20) * 1024 + threadIdx.x;
        if (i < n) { float d = deg[i] + 1.0f; dinv[i] = 1.0f / sqrtf(d); }
    }
}

__global__ void scan_p2_kernel(const int* __restrict__ bsum, int* __restrict__ boffs,
                               int* __restrict__ offs, int n, int nb) {
    int lane = threadIdx.x;   // 64 threads
    int v = (lane < nb) ? bsum[lane] : 0;
    int xv = v;
#pragma unroll
    for (int d = 1; d < 64; d <<= 1) {
        int u = __shfl_up(xv, d, 64);
        if (lane >= d) xv += u;
    }
    if (lane < nb) boffs[lane] = xv - v;
    if (lane == nb - 1) offs[n] = xv;
}

__global__ __launch_bounds__(1024) void scan_p3_kernel(const int* __restrict__ counts,
                                                       const int* __restrict__ boffs,
                                                       int* __restrict__ offs, int n) {
    __shared__ int wsum[16], wpre[16];
    int t = threadIdx.x, lane = t & 63, wid = t >> 6;
    int i = blockIdx.x * 1024 + t;
    int v = (i < n) ? counts[i] : 0;
    int xv = v;
#pragma unroll
    for (int d = 1; d < 64; d <<= 1) {
        int u = __shfl_up(xv, d, 64);
        if (lane >= d) xv += u;
    }
    if (lane == 63) wsum[wid] = xv;
    __syncthreads();
    if (wid == 0) {
        int s = (lane < 16) ? wsum[lane] : 0;
#pragma unroll
        for (int d = 1; d < 16; d <<= 1) {
            int u = __shfl_up(s, d, 64);
            if (lane >= d) s += u;
        }
        if (lane < 16) wpre[lane] = s;
    }
    __syncthreads();
    int prefix = boffs[blockIdx.x] + (wid > 0 ? wpre[wid - 1] : 0);
    if (i < n) offs[i] = prefix + xv - v;
}

__global__ void scatter_kernel(const int* __restrict__ ei, const float* __restrict__ ea,
                               const float* __restrict__ dinv, const int* __restrict__ offs,
                               int* __restrict__ cursor, int* __restrict__ csr_src,
                               float* __restrict__ csr_norm, int E) {
    int e = blockIdx.x * 256 + threadIdx.x;
    if (e >= E) return;
    int src = ei[e];
    int dst = ei[E + e];
    int slot = offs[dst] + atomicAdd(&cursor[dst], 1);
    csr_src[slot] = src;
    csr_norm[slot] = dinv[src] * ea[e] * dinv[dst];
}

// ================= split-bf16 MFMA GEMM: A frags in regs (1-iter prefetch), B dbuf LDS =================
// A never touches LDS: a[mt] fragment regs are reloaded for iter kt+1 right after
// their last use in iter kt (~3/4-iteration prefetch distance, L2-hot via XCD
// swizzle). B register-prefetched into double-buffered LDS; one raw s_barrier
// (lgkm-only drain) per K-iter; B(kt+2) loads stay in flight across it.
// LDS ops/wave/iter: 4 writes + 8 reads (vs 24 with A in LDS) -> MFMA-pipe-bound.

template <int BN, int NCB, bool EMB>
__global__ __launch_bounds__(256, 3) void gemm_areg_kernel(
    const unsigned short* __restrict__ Ah, const unsigned short* __restrict__ Al, int Kp,
    const unsigned short* __restrict__ Bh, const unsigned short* __restrict__ Bl,
    float* __restrict__ C, int ldc, int M,
    const float* __restrict__ T, const int* __restrict__ idx8) {
    constexpr int NT = BN / 32;     // n-tiles per wave
    constexpr int BJ = BN / 64;     // B stage b128 loads per thread per plane
    __shared__ __align__(16) unsigned short sBh[2][BN * 32];
    __shared__ __align__(16) unsigned short sBl[2][BN * 32];

    const int t = threadIdx.x;
    const int lane = t & 63;
    const int w = t >> 6;
    const int wr = w >> 1, wc = w & 1;
    const int l15 = lane & 15, quad = lane >> 4;

    const int total = gridDim.x;
    const int per = total >> 3;
    const int bid = blockIdx.x;
    const int tile = (bid < (per << 3)) ? ((bid & 7) * per + (bid >> 3)) : bid;
    const int row0 = (tile / NCB) * 128;
    const int col0 = (tile % NCB) * BN;

    const int si_r = lane >> 2;                      // B stage: row in 16-row group
    const int si_s = lane & 3;                       // B stage: LDS chunk slot
    const int schunk = si_s ^ ((si_r >> 1) & 3);     // global chunk staged into slot
    const int sw = (quad ^ ((l15 >> 1) & 3)) * 8;    // frag slot offset (ushorts)

    // A frag base pointers (direct global; frag = A[m=l15][k=quad*8+j])
    const unsigned short* pAh[4]; const unsigned short* pAl[4];
#pragma unroll
    for (int mt = 0; mt < 4; ++mt) {
        int r = row0 + wr * 64 + mt * 16 + l15;
        size_t o = (size_t)r * Kp + quad * 8;
        pAh[mt] = Ah + o; pAl[mt] = Al + o;
    }

    // B staging pointers
    const unsigned short* gB[BJ][2];
    int boff[BJ];
#pragma unroll
    for (int j = 0; j < BJ; ++j) {
        int rb = w * (BN / 4) + j * 16 + si_r;
        size_t e = (size_t)(col0 + rb) * Kp + schunk * 8;
        gB[j][0] = Bh + e; gB[j][1] = Bl + e;
        boff[j] = (w * (BN / 4) + j * 16 + si_r) * 32 + si_s * 8;
    }

    f32x4 acc[4][NT];
#pragma unroll
    for (int i = 0; i < 4; ++i)
#pragma unroll
        for (int j = 0; j < NT; ++j)
            acc[i][j] = (f32x4){0.f, 0.f, 0.f, 0.f};

    const int nit = Kp / 32;

    // prologue: A(0) frags into regs; B(0) staged to buf0; B(1) into stage regs
    short8 a_h[4], a_l[4];
#pragma unroll
    for (int mt = 0; mt < 4; ++mt) {
        a_h[mt] = *(g8cp)(const void*)(pAh[mt]);
        a_l[mt] = *(g8cp)(const void*)(pAl[mt]);
    }
    short8 pB[BJ][2];
#pragma unroll
    for (int j = 0; j < BJ; ++j) {
        pB[j][0] = *(g8cp)(const void*)(gB[j][0]);
        pB[j][1] = *(g8cp)(const void*)(gB[j][1]);
    }
#pragma unroll
    for (int j = 0; j < BJ; ++j) {
        *(short8*)&sBh[0][boff[j]] = pB[j][0];
        *(short8*)&sBl[0][boff[j]] = pB[j][1];
    }
#pragma unroll
    for (int j = 0; j < BJ; ++j) {
        pB[j][0] = *(g8cp)(const void*)(gB[j][0] + 32);
        pB[j][1] = *(g8cp)(const void*)(gB[j][1] + 32);
    }
    __builtin_amdgcn_s_waitcnt(0xC07F);   // lgkmcnt(0)
    __builtin_amdgcn_s_barrier();
    __builtin_amdgcn_sched_barrier(0);

    for (int kt = 0; kt < nit; ++kt) {
        const int cur = kt & 1, nxt = cur ^ 1;
        const int kbn = (kt + 1 < nit) ? (kt + 1) * 32 : 0;   // next-iter A offset
        // stage B(kt+1) regs -> LDS buf[nxt]
#pragma unroll
        for (int j = 0; j < BJ; ++j) {
            *(short8*)&sBh[nxt][boff[j]] = pB[j][0];
            *(short8*)&sBl[nxt][boff[j]] = pB[j][1];
        }
        // issue B(kt+2) loads (in flight across barrier)
        {
            const int kb2 = (kt + 2 < nit) ? (kt + 2) * 32 : 0;
#pragma unroll
            for (int j = 0; j < BJ; ++j) {
                pB[j][0] = *(g8cp)(const void*)(gB[j][0] + kb2);
                pB[j][1] = *(g8cp)(const void*)(gB[j][1] + kb2);
            }
        }
        __builtin_amdgcn_s_waitcnt(0xC07F);   // lgkmcnt(0): ds_writes drained
        __builtin_amdgcn_s_barrier();
        __builtin_amdgcn_sched_barrier(0);

        // B frags from LDS buf[cur]
        short8 fbh[NT], fbl[NT];
#pragma unroll
        for (int nt = 0; nt < NT; ++nt) {
            int off = (wc * (BN / 2) + nt * 16 + l15) * 32 + sw;
            fbh[nt] = *(const short8*)&sBh[cur][off];
            fbl[nt] = *(const short8*)&sBl[cur][off];
        }
        // mt groups: consume a[mt], then immediately reload it for kt+1
#pragma unroll
        for (int mt = 0; mt < 4; ++mt) {
#pragma unroll
            for (int nt = 0; nt < NT; ++nt)
                acc[mt][nt] = __builtin_amdgcn_mfma_f32_16x16x32_bf16(a_h[mt], fbh[nt], acc[mt][nt], 0, 0, 0);
#pragma unroll
            for (int nt = 0; nt < NT; ++nt)
                acc[mt][nt] = __builtin_amdgcn_mfma_f32_16x16x32_bf16(a_h[mt], fbl[nt], acc[mt][nt], 0, 0, 0);
#pragma unroll
            for (int nt = 0; nt < NT; ++nt)
                acc[mt][nt] = __builtin_amdgcn_mfma_f32_16x16x32_bf16(a_l[mt], fbh[nt], acc[mt][nt], 0, 0, 0);
            a_h[mt] = *(g8cp)(const void*)(pAh[mt] + kbn);
            a_l[mt] = *(g8cp)(const void*)(pAl[mt] + kbn);
        }
    }

    // epilogue: C/D layout col=lane&15, row=quad*4+r  (+ fused embedding add)
#pragma unroll
    for (int mt = 0; mt < 4; ++mt)
#pragma unroll
        for (int r = 0; r < 4; ++r) {
            int row = row0 + wr * 64 + mt * 16 + quad * 4 + r;
            if (row >= M) continue;
            if (EMB) {
                const int* ix = idx8 + row * 8;
                const float* t0 = T + (size_t)ix[0] * 512;
                const float* t1 = T + (size_t)(3 + ix[1]) * 512;
                const float* t2 = T + (size_t)(14 + ix[2]) * 512;
                const float* t3 = T + (size_t)(270 + ix[3]) * 512;
                const float* t4 = T + (size_t)(526 + ix[4]) * 512;
#pragma unroll
                for (int nt = 0; nt < NT; ++nt) {
                    int col = col0 + wc * (BN / 2) + nt * 16 + l15;
                    float e = t0[col] + t1[col] + t2[col] + t3[col] + t4[col];
                    C[(size_t)row * ldc + col] = acc[mt][nt][r] + e;
                }
            } else {
#pragma unroll
                for (int nt = 0; nt < NT; ++nt) {
                    int col = col0 + wc * (BN / 2) + nt * 16 + l15;
                    C[(size_t)row * ldc + col] = acc[mt][nt][r];
                }
            }
        }
}

// ================= column-sliced aggregation, XCD-pinned chunks =================
// PROJ=true (layer 3): no column slicing (CW=F=64); fused h3@Wp+bp via shuffle.

template <int F, int CW, bool SPLIT, bool PROJ>
__global__ __launch_bounds__(256) void agg_cols_kernel(
    const float* __restrict__ H, const float* __restrict__ dinv,
    const int* __restrict__ offs, const int* __restrict__ csr_src,
    const float* __restrict__ csr_norm, const float* __restrict__ bias,
    float* __restrict__ outf, unsigned short* __restrict__ Hh,
    unsigned short* __restrict__ Hl,
    const float* __restrict__ Wp, const float* __restrict__ bp, int n_nodes) {
    constexpr int LPN = CW / 4;        // lanes per node
    constexpr int NPB = 256 / LPN;     // nodes per block
    constexpr int NCH = F / CW;        // chunks
    constexpr int ECAP = 2048;
    __shared__ int   se[ECAP];
    __shared__ float sn[ECAP];

    const int chunk = blockIdx.x & (NCH - 1);
    const int nb    = blockIdx.x / NCH;
    const int n0 = nb * NPB;
    const int n1 = min(n0 + NPB, n_nodes);
    if (n0 >= n_nodes) return;

    const int estart = offs[n0];
    const int eend   = offs[n1];
    const int ecnt   = eend - estart;
    const bool inlds = (ecnt <= ECAP);
    if (inlds) {
        for (int i = threadIdx.x; i < ecnt; i += 256) {
            se[i] = csr_src[estart + i];
            sn[i] = csr_norm[estart + i];
        }
    }
    __syncthreads();

    const int n = n0 + threadIdx.x / LPN;
    if (n >= n_nodes) return;
    const int lane = threadIdx.x % LPN;
    const int c = chunk * CW + lane * 4;

    float di = dinv[n];
    float s = di * di;
    float4 h = *(const float4*)(H + (size_t)n * F + c);
    float4 acc = make_float4(h.x * s, h.y * s, h.z * s, h.w * s);
    int e0 = offs[n], e1 = offs[n + 1];
    if (inlds) {
        for (int e = e0 - estart; e < e1 - estart; ++e) {
            int src = se[e];
            float w = sn[e];
            float4 v = *(const float4*)(H + (size_t)src * F + c);
            acc.x += v.x * w; acc.y += v.y * w; acc.z += v.z * w; acc.w += v.w * w;
        }
    } else {
        for (int e = e0; e < e1; ++e) {
            int src = csr_src[e];
            float w = csr_norm[e];
            float4 v = *(const float4*)(H + (size_t)src * F + c);
            acc.x += v.x * w; acc.y += v.y * w; acc.z += v.z * w; acc.w += v.w * w;
        }
    }
    float4 b = *(const float4*)(bias + c);
    acc.x += b.x; acc.y += b.y; acc.z += b.z; acc.w += b.w;
    acc.x = acc.x > 0.f ? acc.x : 0.01f * acc.x;
    acc.y = acc.y > 0.f ? acc.y : 0.01f * acc.y;
    acc.z = acc.z > 0.f ? acc.z : 0.01f * acc.z;
    acc.w = acc.w > 0.f ? acc.w : 0.01f * acc.w;
    if (PROJ) {
        // fused projection: out[n] = h3[n] @ Wp + bp; reduce over LPN=16 lanes
        float p[3];
#pragma unroll
        for (int j = 0; j < 3; ++j)
            p[j] = acc.x * Wp[(c + 0) * 3 + j] + acc.y * Wp[(c + 1) * 3 + j] +
                   acc.z * Wp[(c + 2) * 3 + j] + acc.w * Wp[(c + 3) * 3 + j];
#pragma unroll
        for (int d = 1; d < LPN; d <<= 1) {
#pragma unroll
            for (int j = 0; j < 3; ++j)
                p[j] += __shfl_xor(p[j], d, 64);
        }
        if (lane == 0) {
#pragma unroll
            for (int j = 0; j < 3; ++j)
                outf[n * 3 + j] = p[j] + bp[j];
        }
    } else if (SPLIT) {
        u16x4 hh, ll;
        unsigned short a, bb;
        split1(acc.x, a, bb); hh[0] = (short)a; ll[0] = (short)bb;
        split1(acc.y, a, bb); hh[1] = (short)a; ll[1] = (short)bb;
        split1(acc.z, a, bb); hh[2] = (short)a; ll[2] = (short)bb;
        split1(acc.w, a, bb); hh[3] = (short)a; ll[3] = (short)bb;
        *(u16x4*)(Hh + (size_t)n * F + c) = hh;
        *(u16x4*)(Hl + (size_t)n * F + c) = ll;
    } else {
        *(float4*)(outf + (size_t)n * F + c) = acc;
    }
}

// ================= launch =================

static inline size_t aln(size_t v) { return (v + 255) & ~(size_t)255; }

extern "C" void kernel_launch(void* const* d_in, const int* in_sizes, int n_in,
                              void* d_out, int out_size, void* d_ws, size_t ws_size,
                              hipStream_t stream) {
    const float* x           = (const float*)d_in[0];
    const int*   edge_index  = (const int*)d_in[1];
    const float* edge_attr   = (const float*)d_in[2];
    const float* layer_table = (const float*)d_in[3];
    const float* rel_table   = (const float*)d_in[4];
    const float* color_table = (const float*)d_in[5];
    const float* W1 = (const float*)d_in[6];
    const float* b1 = (const float*)d_in[7];
    const float* W2 = (const float*)d_in[8];
    const float* b2 = (const float*)d_in[9];
    const float* W3 = (const float*)d_in[10];
    const float* b3 = (const float*)d_in[11];
    const float* Wp = (const float*)d_in[12];
    const float* bp = (const float*)d_in[13];
    float* out = (float*)d_out;

    const int N = NNODES, E = NEDGES;

    char* p = (char*)d_ws;
    // zero region: deg + counts + cursor contiguous -> single memset
    float* deg      = (float*)p;
    int*   counts   = (int*)(p + (size_t)N * 4);
    int*   cursor   = (int*)(p + (size_t)N * 8);     p += aln((size_t)N * 12);
    float* dinv     = (float*)p; p += aln((size_t)N * 4);
    float* T        = (float*)p; p += aln((size_t)782 * 512 * 4);
    float* csr_norm = (float*)p; p += aln((size_t)E * 4);
    float* C        = (float*)p; p += aln((size_t)MP * 512 * 4);
    unsigned short* BIG = (unsigned short*)p; p += aln((size_t)MP * 2048 * 2);
    unsigned short* Bt1h = (unsigned short*)p; p += aln((size_t)512 * 1024 * 2);
    unsigned short* Bt1l = (unsigned short*)p; p += aln((size_t)512 * 1024 * 2);
    unsigned short* Bt2h = (unsigned short*)p; p += aln((size_t)256 * 512 * 2);
    unsigned short* Bt2l = (unsigned short*)p; p += aln((size_t)256 * 512 * 2);
    unsigned short* Bt3h = (unsigned short*)p; p += aln((size_t)64 * 256 * 2);
    unsigned short* Bt3l = (unsigned short*)p; p += aln((size_t)64 * 256 * 2);
    int*   csr_src  = (int*)p;   p += aln((size_t)E * 4);
    int*   idx8     = (int*)p;   p += aln((size_t)N * 8 * 4);
    int*   offs     = (int*)p;   p += aln((size_t)(N + 1) * 4);
    int*   bsum     = (int*)p;   p += aln((size_t)32 * 4);
    int*   boffs    = (int*)p;   p += aln((size_t)32 * 4);

    unsigned short* A1h = BIG;
    unsigned short* A1l = BIG + (size_t)MP * 1024;
    unsigned short* H2h = BIG;
    unsigned short* H2l = BIG + (size_t)MP * 512;
    unsigned short* H3h = BIG + (size_t)MP * 1024;
    unsigned short* H3l = BIG + (size_t)MP * 1024 + (size_t)MP * 256;

    hipMemsetAsync(deg, 0, (size_t)N * 12, stream);

    prep_kernel<<<PB_TAB, 256, 0, stream>>>(
        x, edge_index, edge_attr, layer_table, rel_table, color_table,
        W1, W2, W3, deg, counts, idx8,
        A1h, A1l, Bt1h, Bt1l, Bt2h, Bt2l, Bt3h, Bt3l, T);

    scan_p1_kernel<<<40, 1024, 0, stream>>>(counts, bsum, deg, dinv, N);
    scan_p2_kernel<<<1, 64, 0, stream>>>(bsum, boffs, offs, N, 20);
    scan_p3_kernel<<<20, 1024, 0, stream>>>(counts, boffs, offs, N);
    scatter_kernel<<<(E + 255) / 256, 256, 0, stream>>>(edge_index, edge_attr, dinv, offs,
                                                        cursor, csr_src, csr_norm, E);

    const int nrb = MP / 128;   // 157 row bands

    // layer 1
    {
        gemm_areg_kernel<128, 4, true><<<nrb * 4, 256, 0, stream>>>(
            A1h, A1l, 1024, Bt1h, Bt1l, C, 512, N, T, idx8);
        int nblocks = (N + 15) / 16;           // NPB=16
        agg_cols_kernel<512, 64, true, false><<<8 * nblocks, 256, 0, stream>>>(
            C, dinv, offs, csr_src, csr_norm, b1, nullptr, H2h, H2l, nullptr, nullptr, N);
    }
    // layer 2
    {
        gemm_areg_kernel<128, 2, false><<<nrb * 2, 256, 0, stream>>>(
            H2h, H2l, 512, Bt2h, Bt2l, C, 256, N, nullptr, nullptr);
        int nblocks = (N + 31) / 32;           // NPB=32
        agg_cols_kernel<256, 32, true, false><<<8 * nblocks, 256, 0, stream>>>(
            C, dinv, offs, csr_src, csr_norm, b2, nullptr, H3h, H3l, nullptr, nullptr, N);
    }
    // layer 3 (+ fused projection)
    {
        gemm_areg_kernel<64, 1, false><<<nrb, 256, 0, stream>>>(
            H3h, H3l, 256, Bt3h, Bt3l, C, 64, N, nullptr, nullptr);
        int nblocks = (N + 15) / 16;           // NPB=16, no column slicing
        agg_cols_kernel<64, 64, false, true><<<nblocks, 256, 0, stream>>>(
            C, dinv, offs, csr_src, csr_norm, b3, out, nullptr, nullptr, Wp, bp, N);
    }
}

// Round 10
// 445.838 us; speedup vs baseline: 1.1821x; 1.1821x over previous
//
#include <hip/hip_runtime.h>
#include <hip/hip_bf16.h>

#define NNODES 20000
#define NEDGES 320000
#define XW 1005          // x row width: 1 + 1000 + 1 + 3
#define MP 20096         // 314 * 64 row-padded M

typedef __attribute__((ext_vector_type(8))) short short8;
typedef __attribute__((ext_vector_type(4))) float f32x4;
typedef __attribute__((ext_vector_type(4))) unsigned short u16x4;

typedef const __attribute__((address_space(1))) short8* g8cp;

__device__ inline void split1(float v, unsigned short& h, unsigned short& l) {
    unsigned u = __float_as_uint(v);
    h = (unsigned short)(u >> 16);
    float hf = __uint_as_float(u & 0xffff0000u);
    l = (unsigned short)(__float_as_uint(v - hf) >> 16);
}

// ================= fused prep über-kernel =================
#define PB_EDGE  1250
#define PB_IDX   1329
#define PB_A1    21329
#define PB_BT1   21841
#define PB_BT2   21969
#define PB_BT3   21985
#define PB_TAB   23549

__device__ inline void bt_split_body(int g, const float* __restrict__ W, int ldw,
                                     int koff, int K, int Kp, int Ncols,
                                     unsigned short* __restrict__ Bh,
                                     unsigned short* __restrict__ Bl) {
    int kp4 = Kp >> 2;
    if (g >= Ncols * kp4) return;
    int n = g / kp4, c4 = (g % kp4) << 2;
    u16x4 h, l;
#pragma unroll
    for (int i = 0; i < 4; ++i) {
        int k = c4 + i;
        float v = (k < K) ? W[(size_t)(koff + k) * ldw + n] : 0.0f;
        unsigned short hh, ll;
        split1(v, hh, ll);
        h[i] = (short)hh; l[i] = (short)ll;
    }
    *(u16x4*)&Bh[(size_t)n * Kp + c4] = h;
    *(u16x4*)&Bl[(size_t)n * Kp + c4] = l;
}

__global__ __launch_bounds__(256) void prep_kernel(
    const float* __restrict__ x, const int* __restrict__ ei, const float* __restrict__ ea,
    const float* __restrict__ layer_table, const float* __restrict__ rel_table,
    const float* __restrict__ color_table,
    const float* __restrict__ W1, const float* __restrict__ W2, const float* __restrict__ W3,
    float* __restrict__ deg, int* __restrict__ counts, int* __restrict__ idx8,
    unsigned short* __restrict__ A1h, unsigned short* __restrict__ A1l,
    unsigned short* __restrict__ Bt1h, unsigned short* __restrict__ Bt1l,
    unsigned short* __restrict__ Bt2h, unsigned short* __restrict__ Bt2l,
    unsigned short* __restrict__ Bt3h, unsigned short* __restrict__ Bt3l,
    float* __restrict__ T) {
    const int b = blockIdx.x;
    const int t = threadIdx.x;
    if (b < PB_EDGE) {
        int e = b * 256 + t;
        if (e >= NEDGES) return;
        int dst = ei[NEDGES + e];
        atomicAdd(&deg[dst], ea[e]);
        atomicAdd(&counts[dst], 1);
    } else if (b < PB_IDX) {
        int i = (b - PB_EDGE) * 256 + t;
        if (i >= NNODES) return;
        const float* r = x + (size_t)i * XW;
        idx8[i * 8 + 0] = (int)(r[0] - 1.0f);
        idx8[i * 8 + 1] = (int)rintf(fabsf(r[1001]) * 10.0f);
        idx8[i * 8 + 2] = (int)r[1002];
        idx8[i * 8 + 3] = (int)r[1003];
        idx8[i * 8 + 4] = (int)r[1004];
    } else if (b < PB_A1) {
        int row = b - PB_IDX;                  // one block per node
        int c4 = t << 2;
        const float* xp = x + (size_t)row * XW + 1 + c4;
        u16x4 h, l;
#pragma unroll
        for (int i = 0; i < 4; ++i) {
            float v = (c4 + i < 1000) ? xp[i] : 0.0f;
            unsigned short hh, ll;
            split1(v, hh, ll);
            h[i] = (short)hh; l[i] = (short)ll;
        }
        *(u16x4*)&A1h[(size_t)row * 1024 + c4] = h;
        *(u16x4*)&A1l[(size_t)row * 1024 + c4] = l;
    } else if (b < PB_BT1) {
        bt_split_body((b - PB_A1) * 256 + t, W1, 512, 250, 1000, 1024, 512, Bt1h, Bt1l);
    } else if (b < PB_BT2) {
        bt_split_body((b - PB_BT1) * 256 + t, W2, 256, 0, 512, 512, 256, Bt2h, Bt2l);
    } else if (b < PB_BT3) {
        bt_split_body((b - PB_BT2) * 256 + t, W3, 64, 0, 256, 256, 64, Bt3h, Bt3l);
    } else {
        int g = (b - PB_BT3) * 256 + t;
        if (g >= 782 * 512) return;
        int row = g >> 9, col = g & 511;
        float acc = 0.0f;
        if (row < 3) {
            for (int k = 0; k < 250; ++k)
                acc += layer_table[row * 250 + k] * W1[(size_t)k * 512 + col];
        } else if (row < 14) {
            int r = row - 3;
            for (int k = 0; k < 250; ++k)
                acc += rel_table[r * 250 + k] * W1[(size_t)(1250 + k) * 512 + col];
        } else {
            int r = row - 14;
            int j = r >> 8, v = r & 255;
            int base = 1500 + 85 * j;
            for (int k = 0; k < 85; ++k)
                acc += color_table[v * 85 + k] * W1[(size_t)(base + k) * 512 + col];
        }
        T[(size_t)row * 512 + col] = acc;
    }
}

// ================= 3-phase parallel scan (+ dinv folded into phase 1) =================

__global__ __launch_bounds__(1024) void scan_p1_kernel(const int* __restrict__ counts,
                                                       int* __restrict__ bsum,
                                                       const float* __restrict__ deg,
                                                       float* __restrict__ dinv, int n) {
    int b = blockIdx.x;
    if (b < 20) {
        __shared__ int ws[16];
        int t = threadIdx.x, lane = t & 63, wid = t >> 6;
        int i = b * 1024 + t;
        int v = (i < n) ? counts[i] : 0;
#pragma unroll
        for (int d = 32; d; d >>= 1) v += __shfl_down(v, d, 64);
        if (lane == 0) ws[wid] = v;
        __syncthreads();
        if (wid == 0) {
            int s = (lane < 16) ? ws[lane] : 0;
#pragma unroll
            for (int d = 8; d; d >>= 1) s += __shfl_down(s, d, 64);
            if (lane == 0) bsum[b] = s;
        }
    } else {
        int i = (b - 20) * 1024 + threadIdx.x;
        if (i < n) { float d = deg[i] + 1.0f; dinv[i] = 1.0f / sqrtf(d); }
    }
}

__global__ void scan_p2_kernel(const int* __restrict__ bsum, int* __restrict__ boffs,
                               int* __restrict__ offs, int n, int nb) {
    int lane = threadIdx.x;   // 64 threads
    int v = (lane < nb) ? bsum[lane] : 0;
    int xv = v;
#pragma unroll
    for (int d = 1; d < 64; d <<= 1) {
        int u = __shfl_up(xv, d, 64);
        if (lane >= d) xv += u;
    }
    if (lane < nb) boffs[lane] = xv - v;
    if (lane == nb - 1) offs[n] = xv;
}

__global__ __launch_bounds__(1024) void scan_p3_kernel(const int* __restrict__ counts,
                                                       const int* __restrict__ boffs,
                                                       int* __restrict__ offs, int n) {
    __shared__ int wsum[16], wpre[16];
    int t = threadIdx.x, lane = t & 63, wid = t >> 6;
    int i = blockIdx.x * 1024 + t;
    int v = (i < n) ? counts[i] : 0;
    int xv = v;
#pragma unroll
    for (int d = 1; d < 64; d <<= 1) {
        int u = __shfl_up(xv, d, 64);
        if (lane >= d) xv += u;
    }
    if (lane == 63) wsum[wid] = xv;
    __syncthreads();
    if (wid == 0) {
        int s = (lane < 16) ? wsum[lane] : 0;
#pragma unroll
        for (int d = 1; d < 16; d <<= 1) {
            int u = __shfl_up(s, d, 64);
            if (lane >= d) s += u;
        }
        if (lane < 16) wpre[lane] = s;
    }
    __syncthreads();
    int prefix = boffs[blockIdx.x] + (wid > 0 ? wpre[wid - 1] : 0);
    if (i < n) offs[i] = prefix + xv - v;
}

__global__ void scatter_kernel(const int* __restrict__ ei, const float* __restrict__ ea,
                               const float* __restrict__ dinv, const int* __restrict__ offs,
                               int* __restrict__ cursor, int* __restrict__ csr_src,
                               float* __restrict__ csr_norm, int E) {
    int e = blockIdx.x * 256 + threadIdx.x;
    if (e >= E) return;
    int src = ei[e];
    int dst = ei[E + e];
    int slot = offs[dst] + atomicAdd(&cursor[dst], 1);
    csr_src[slot] = src;
    csr_norm[slot] = dinv[src] * ea[e] * dinv[dst];
}

// ================= split-bf16 MFMA GEMM: R7 pipeline, BM=64 for 2x grid =================
// Reg-prefetch -> single-stage LDS -> raw lgkm-only barriers (proven best, R7).
// BM 128->64 doubles the grid (1256/628/314 blocks = 4.9/2.45/1.2 per CU) and cuts
// LDS to 24 KB -> occupancy-driven latency hiding for the 2-barrier K-loop.
// Per iteration: ds_write regs->LDS (vmcnt for prev prefetch lands here); issue
// kt+1 global loads (in flight across barrier); lgkm-wait + s_barrier; ds_read
// frags; 3 MFMA passes (hh+hl+lh); release s_barrier.

template <int BN, int NCB, bool EMB>
__global__ __launch_bounds__(256, 3) void gemm_bm64_kernel(
    const unsigned short* __restrict__ Ah, const unsigned short* __restrict__ Al, int Kp,
    const unsigned short* __restrict__ Bh, const unsigned short* __restrict__ Bl,
    float* __restrict__ C, int ldc, int M,
    const float* __restrict__ T, const int* __restrict__ idx8) {
    constexpr int NT = BN / 32;     // n-tiles per wave (wave covers 32 x BN/2)
    constexpr int BJ = BN / 64;     // B staging b128 loads per thread per plane
    __shared__ __align__(16) unsigned short sAh[64 * 32];
    __shared__ __align__(16) unsigned short sAl[64 * 32];
    __shared__ __align__(16) unsigned short sBh[BN * 32];
    __shared__ __align__(16) unsigned short sBl[BN * 32];

    const int t = threadIdx.x;
    const int lane = t & 63;
    const int w = t >> 6;
    const int wr = w >> 1, wc = w & 1;
    const int l15 = lane & 15, quad = lane >> 4;

    const int total = gridDim.x;
    const int per = total >> 3;
    const int bid = blockIdx.x;
    const int tile = (bid < (per << 3)) ? ((bid & 7) * per + (bid >> 3)) : bid;
    const int row0 = (tile / NCB) * 64;
    const int col0 = (tile % NCB) * BN;

    const int si_r = lane >> 2;                      // row within 16-row group
    const int si_s = lane & 3;                       // LDS chunk slot
    const int schunk = si_s ^ ((si_r >> 1) & 3);     // global chunk staged into slot
    const int sw = (quad ^ ((l15 >> 1) & 3)) * 8;    // fragment slot offset (ushorts)

    // staging: A 64 rows = 4 waves x 16; B BN rows = 4 waves x BJ x 16
    const unsigned short* gA[2];
    int aoff;
    {
        int ra = w * 16 + si_r;
        size_t e = (size_t)(row0 + ra) * Kp + schunk * 8;
        gA[0] = Ah + e; gA[1] = Al + e;
        aoff = (w * 16 + si_r) * 32 + si_s * 8;
    }
    const unsigned short* gB[BJ][2];
    int boff[BJ];
#pragma unroll
    for (int j = 0; j < BJ; ++j) {
        int rb = w * (BN / 4) + j * 16 + si_r;
        size_t e = (size_t)(col0 + rb) * Kp + schunk * 8;
        gB[j][0] = Bh + e; gB[j][1] = Bl + e;
        boff[j] = (w * (BN / 4) + j * 16 + si_r) * 32 + si_s * 8;
    }

    f32x4 acc[2][NT];
#pragma unroll
    for (int i = 0; i < 2; ++i)
#pragma unroll
        for (int j = 0; j < NT; ++j)
            acc[i][j] = (f32x4){0.f, 0.f, 0.f, 0.f};

    const int nit = Kp / 32;

    // preload tile 0 into regs
    short8 pA[2], pB[BJ][2];
    pA[0] = *(g8cp)(const void*)(gA[0]);
    pA[1] = *(g8cp)(const void*)(gA[1]);
#pragma unroll
    for (int j = 0; j < BJ; ++j) {
        pB[j][0] = *(g8cp)(const void*)(gB[j][0]);
        pB[j][1] = *(g8cp)(const void*)(gB[j][1]);
    }

    for (int kt = 0; kt < nit; ++kt) {
        // stage regs -> LDS (compiler inserts vmcnt wait for the prefetch here)
        *(short8*)&sAh[aoff] = pA[0];
        *(short8*)&sAl[aoff] = pA[1];
#pragma unroll
        for (int j = 0; j < BJ; ++j) {
            *(short8*)&sBh[boff[j]] = pB[j][0];
            *(short8*)&sBl[boff[j]] = pB[j][1];
        }
        // issue next tile's loads (stay in flight across the barrier)
        if (kt + 1 < nit) {
            const int kb = (kt + 1) * 32;
            pA[0] = *(g8cp)(const void*)(gA[0] + kb);
            pA[1] = *(g8cp)(const void*)(gA[1] + kb);
#pragma unroll
            for (int j = 0; j < BJ; ++j) {
                pB[j][0] = *(g8cp)(const void*)(gB[j][0] + kb);
                pB[j][1] = *(g8cp)(const void*)(gB[j][1] + kb);
            }
        }
        __builtin_amdgcn_s_waitcnt(0xC07F);   // lgkmcnt(0) only — ds_writes drained
        __builtin_amdgcn_s_barrier();
        __builtin_amdgcn_sched_barrier(0);    // keep frag reads below the barrier

        short8 fah[2], fal[2], fbh[NT], fbl[NT];
#pragma unroll
        for (int mt = 0; mt < 2; ++mt) {
            int off = (wr * 32 + mt * 16 + l15) * 32 + sw;
            fah[mt] = *(const short8*)&sAh[off];
            fal[mt] = *(const short8*)&sAl[off];
        }
#pragma unroll
        for (int nt = 0; nt < NT; ++nt) {
            int off = (wc * (BN / 2) + nt * 16 + l15) * 32 + sw;
            fbh[nt] = *(const short8*)&sBh[off];
            fbl[nt] = *(const short8*)&sBl[off];
        }
#pragma unroll
        for (int mt = 0; mt < 2; ++mt)
#pragma unroll
            for (int nt = 0; nt < NT; ++nt)
                acc[mt][nt] = __builtin_amdgcn_mfma_f32_16x16x32_bf16(fah[mt], fbh[nt], acc[mt][nt], 0, 0, 0);
#pragma unroll
        for (int mt = 0; mt < 2; ++mt)
#pragma unroll
            for (int nt = 0; nt < NT; ++nt)
                acc[mt][nt] = __builtin_amdgcn_mfma_f32_16x16x32_bf16(fah[mt], fbl[nt], acc[mt][nt], 0, 0, 0);
#pragma unroll
        for (int mt = 0; mt < 2; ++mt)
#pragma unroll
            for (int nt = 0; nt < NT; ++nt)
                acc[mt][nt] = __builtin_amdgcn_mfma_f32_16x16x32_bf16(fal[mt], fbh[nt], acc[mt][nt], 0, 0, 0);
        if (kt + 1 < nit) __builtin_amdgcn_s_barrier();   // release LDS for next stage
    }

    // epilogue: C/D layout col=lane&15, row=quad*4+r  (+ fused embedding add)
#pragma unroll
    for (int mt = 0; mt < 2; ++mt)
#pragma unroll
        for (int r = 0; r < 4; ++r) {
            int row = row0 + wr * 32 + mt * 16 + quad * 4 + r;
            if (row >= M) continue;
            if (EMB) {
                const int* ix = idx8 + row * 8;
                const float* t0 = T + (size_t)ix[0] * 512;
                const float* t1 = T + (size_t)(3 + ix[1]) * 512;
                const float* t2 = T + (size_t)(14 + ix[2]) * 512;
                const float* t3 = T + (size_t)(270 + ix[3]) * 512;
                const float* t4 = T + (size_t)(526 + ix[4]) * 512;
#pragma unroll
                for (int nt = 0; nt < NT; ++nt) {
                    int col = col0 + wc * (BN / 2) + nt * 16 + l15;
                    float e = t0[col] + t1[col] + t2[col] + t3[col] + t4[col];
                    C[(size_t)row * ldc + col] = acc[mt][nt][r] + e;
                }
            } else {
#pragma unroll
                for (int nt = 0; nt < NT; ++nt) {
                    int col = col0 + wc * (BN / 2) + nt * 16 + l15;
                    C[(size_t)row * ldc + col] = acc[mt][nt][r];
                }
            }
        }
}

// ================= column-sliced aggregation, XCD-pinned chunks =================
// PROJ=true (layer 3): no column slicing (CW=F=64); fused h3@Wp+bp via shuffle.

template <int F, int CW, bool SPLIT, bool PROJ>
__global__ __launch_bounds__(256) void agg_cols_kernel(
    const float* __restrict__ H, const float* __restrict__ dinv,
    const int* __restrict__ offs, const int* __restrict__ csr_src,
    const float* __restrict__ csr_norm, const float* __restrict__ bias,
    float* __restrict__ outf, unsigned short* __restrict__ Hh,
    unsigned short* __restrict__ Hl,
    const float* __restrict__ Wp, const float* __restrict__ bp, int n_nodes) {
    constexpr int LPN = CW / 4;        // lanes per node
    constexpr int NPB = 256 / LPN;     // nodes per block
    constexpr int NCH = F / CW;        // chunks
    constexpr int ECAP = 2048;
    __shared__ int   se[ECAP];
    __shared__ float sn[ECAP];

    const int chunk = blockIdx.x & (NCH - 1);
    const int nb    = blockIdx.x / NCH;
    const int n0 = nb * NPB;
    const int n1 = min(n0 + NPB, n_nodes);
    if (n0 >= n_nodes) return;

    const int estart = offs[n0];
    const int eend   = offs[n1];
    const int ecnt   = eend - estart;
    const bool inlds = (ecnt <= ECAP);
    if (inlds) {
        for (int i = threadIdx.x; i < ecnt; i += 256) {
            se[i] = csr_src[estart + i];
            sn[i] = csr_norm[estart + i];
        }
    }
    __syncthreads();

    const int n = n0 + threadIdx.x / LPN;
    if (n >= n_nodes) return;
    const int lane = threadIdx.x % LPN;
    const int c = chunk * CW + lane * 4;

    float di = dinv[n];
    float s = di * di;
    float4 h = *(const float4*)(H + (size_t)n * F + c);
    float4 acc = make_float4(h.x * s, h.y * s, h.z * s, h.w * s);
    int e0 = offs[n], e1 = offs[n + 1];
    if (inlds) {
        for (int e = e0 - estart; e < e1 - estart; ++e) {
            int src = se[e];
            float w = sn[e];
            float4 v = *(const float4*)(H + (size_t)src * F + c);
            acc.x += v.x * w; acc.y += v.y * w; acc.z += v.z * w; acc.w += v.w * w;
        }
    } else {
        for (int e = e0; e < e1; ++e) {
            int src = csr_src[e];
            float w = csr_norm[e];
            float4 v = *(const float4*)(H + (size_t)src * F + c);
            acc.x += v.x * w; acc.y += v.y * w; acc.z += v.z * w; acc.w += v.w * w;
        }
    }
    float4 b = *(const float4*)(bias + c);
    acc.x += b.x; acc.y += b.y; acc.z += b.z; acc.w += b.w;
    acc.x = acc.x > 0.f ? acc.x : 0.01f * acc.x;
    acc.y = acc.y > 0.f ? acc.y : 0.01f * acc.y;
    acc.z = acc.z > 0.f ? acc.z : 0.01f * acc.z;
    acc.w = acc.w > 0.f ? acc.w : 0.01f * acc.w;
    if (PROJ) {
        // fused projection: out[n] = h3[n] @ Wp + bp; reduce over LPN=16 lanes
        float p[3];
#pragma unroll
        for (int j = 0; j < 3; ++j)
            p[j] = acc.x * Wp[(c + 0) * 3 + j] + acc.y * Wp[(c + 1) * 3 + j] +
                   acc.z * Wp[(c + 2) * 3 + j] + acc.w * Wp[(c + 3) * 3 + j];
#pragma unroll
        for (int d = 1; d < LPN; d <<= 1) {
#pragma unroll
            for (int j = 0; j < 3; ++j)
                p[j] += __shfl_xor(p[j], d, 64);
        }
        if (lane == 0) {
#pragma unroll
            for (int j = 0; j < 3; ++j)
                outf[n * 3 + j] = p[j] + bp[j];
        }
    } else if (SPLIT) {
        u16x4 hh, ll;
        unsigned short a, bb;
        split1(acc.x, a, bb); hh[0] = (short)a; ll[0] = (short)bb;
        split1(acc.y, a, bb); hh[1] = (short)a; ll[1] = (short)bb;
        split1(acc.z, a, bb); hh[2] = (short)a; ll[2] = (short)bb;
        split1(acc.w, a, bb); hh[3] = (short)a; ll[3] = (short)bb;
        *(u16x4*)(Hh + (size_t)n * F + c) = hh;
        *(u16x4*)(Hl + (size_t)n * F + c) = ll;
    } else {
        *(float4*)(outf + (size_t)n * F + c) = acc;
    }
}

// ================= launch =================

static inline size_t aln(size_t v) { return (v + 255) & ~(size_t)255; }

extern "C" void kernel_launch(void* const* d_in, const int* in_sizes, int n_in,
                              void* d_out, int out_size, void* d_ws, size_t ws_size,
                              hipStream_t stream) {
    const float* x           = (const float*)d_in[0];
    const int*   edge_index  = (const int*)d_in[1];
    const float* edge_attr   = (const float*)d_in[2];
    const float* layer_table = (const float*)d_in[3];
    const float* rel_table   = (const float*)d_in[4];
    const float* color_table = (const float*)d_in[5];
    const float* W1 = (const float*)d_in[6];
    const float* b1 = (const float*)d_in[7];
    const float* W2 = (const float*)d_in[8];
    const float* b2 = (const float*)d_in[9];
    const float* W3 = (const float*)d_in[10];
    const float* b3 = (const float*)d_in[11];
    const float* Wp = (const float*)d_in[12];
    const float* bp = (const float*)d_in[13];
    float* out = (float*)d_out;

    const int N = NNODES, E = NEDGES;

    char* p = (char*)d_ws;
    // zero region: deg + counts + cursor contiguous -> single memset
    float* deg      = (float*)p;
    int*   counts   = (int*)(p + (size_t)N * 4);
    int*   cursor   = (int*)(p + (size_t)N * 8);     p += aln((size_t)N * 12);
    float* dinv     = (float*)p; p += aln((size_t)N * 4);
    float* T        = (float*)p; p += aln((size_t)782 * 512 * 4);
    float* csr_norm = (float*)p; p += aln((size_t)E * 4);
    float* C        = (float*)p; p += aln((size_t)MP * 512 * 4);
    unsigned short* BIG = (unsigned short*)p; p += aln((size_t)MP * 2048 * 2);
    unsigned short* Bt1h = (unsigned short*)p; p += aln((size_t)512 * 1024 * 2);
    unsigned short* Bt1l = (unsigned short*)p; p += aln((size_t)512 * 1024 * 2);
    unsigned short* Bt2h = (unsigned short*)p; p += aln((size_t)256 * 512 * 2);
    unsigned short* Bt2l = (unsigned short*)p; p += aln((size_t)256 * 512 * 2);
    unsigned short* Bt3h = (unsigned short*)p; p += aln((size_t)64 * 256 * 2);
    unsigned short* Bt3l = (unsigned short*)p; p += aln((size_t)64 * 256 * 2);
    int*   csr_src  = (int*)p;   p += aln((size_t)E * 4);
    int*   idx8     = (int*)p;   p += aln((size_t)N * 8 * 4);
    int*   offs     = (int*)p;   p += aln((size_t)(N + 1) * 4);
    int*   bsum     = (int*)p;   p += aln((size_t)32 * 4);
    int*   boffs    = (int*)p;   p += aln((size_t)32 * 4);

    unsigned short* A1h = BIG;
    unsigned short* A1l = BIG + (size_t)MP * 1024;
    unsigned short* H2h = BIG;
    unsigned short* H2l = BIG + (size_t)MP * 512;
    unsigned short* H3h = BIG + (size_t)MP * 1024;
    unsigned short* H3l = BIG + (size_t)MP * 1024 + (size_t)MP * 256;

    hipMemsetAsync(deg, 0, (size_t)N * 12, stream);

    prep_kernel<<<PB_TAB, 256, 0, stream>>>(
        x, edge_index, edge_attr, layer_table, rel_table, color_table,
        W1, W2, W3, deg, counts, idx8,
        A1h, A1l, Bt1h, Bt1l, Bt2h, Bt2l, Bt3h, Bt3l, T);

    scan_p1_kernel<<<40, 1024, 0, stream>>>(counts, bsum, deg, dinv, N);
    scan_p2_kernel<<<1, 64, 0, stream>>>(bsum, boffs, offs, N, 20);
    scan_p3_kernel<<<20, 1024, 0, stream>>>(counts, boffs, offs, N);
    scatter_kernel<<<(E + 255) / 256, 256, 0, stream>>>(edge_index, edge_attr, dinv, offs,
                                                        cursor, csr_src, csr_norm, E);

    const int nrb = MP / 64;   // 314 row bands

    // layer 1
    {
        gemm_bm64_kernel<128, 4, true><<<nrb * 4, 256, 0, stream>>>(
            A1h, A1l, 1024, Bt1h, Bt1l, C, 512, N, T, idx8);
        int nblocks = (N + 15) / 16;           // NPB=16
        agg_cols_kernel<512, 64, true, false><<<8 * nblocks, 256, 0, stream>>>(
            C, dinv, offs, csr_src, csr_norm, b1, nullptr, H2h, H2l, nullptr, nullptr, N);
    }
    // layer 2
    {
        gemm_bm64_kernel<128, 2, false><<<nrb * 2, 256, 0, stream>>>(
            H2h, H2l, 512, Bt2h, Bt2l, C, 256, N, nullptr, nullptr);
        int nblocks = (N + 31) / 32;           // NPB=32
        agg_cols_kernel<256, 32, true, false><<<8 * nblocks, 256, 0, stream>>>(
            C, dinv, offs, csr_src, csr_norm, b2, nullptr, H3h, H3l, nullptr, nullptr, N);
    }
    // layer 3 (+ fused projection)
    {
        gemm_bm64_kernel<64, 1, false><<<nrb, 256, 0, stream>>>(
            H3h, H3l, 256, Bt3h, Bt3l, C, 64, N, nullptr, nullptr);
        int nblocks = (N + 15) / 16;           // NPB=16, no column slicing
        agg_cols_kernel<64, 64, false, true><<<nblocks, 256, 0, stream>>>(
            C, dinv, offs, csr_src, csr_norm, b3, out, nullptr, nullptr, Wp, bp, N);
    }
}